// Round 1
// baseline (1333.838 us; speedup 1.0000x reference)
//
#include <hip/hip_runtime.h>
#include <math.h>

// Problem constants (match reference)
constexpr int EN = 200000;   // edges == nodes
constexpr int D  = 128;      // embedding dim
constexpr int R  = 4;        // relation types
constexpr float NEG = 0.01f;

// GEMM tiling
constexpr int TM = 64;       // edges per tile
constexpr int KC = 32;       // K-chunk staged in LDS

static inline int ceil_div(int a, int b) { return (a + b - 1) / b; }

// ---------- degree / norm ----------
__global__ void k_deg(const int* __restrict__ col, float* __restrict__ deg, int n) {
    int e = blockIdx.x * 256 + threadIdx.x;
    if (e < n) atomicAdd(&deg[col[e]], 1.0f);
}

__global__ void k_dinv(float* __restrict__ deg, int n) {
    int i = blockIdx.x * 256 + threadIdx.x;
    if (i < n) {
        float d = deg[i];
        deg[i] = (d > 0.f) ? rsqrtf(d) : 0.f;
    }
}

__global__ void k_coef(const int* __restrict__ row, const int* __restrict__ col,
                       const float* __restrict__ attr, const float* __restrict__ dinv,
                       float* __restrict__ coef, int n) {
    int e = blockIdx.x * 256 + threadIdx.x;
    if (e < n) coef[e] = attr[e] * dinv[row[e]] * dinv[col[e]];
}

// ---------- relation bucketing ----------
__global__ void k_cursor_init(int* __restrict__ cursor) {
    int t = threadIdx.x;
    if (t < R) cursor[t] = t * EN;
}

__global__ void k_bucket(const int* __restrict__ etype, int* __restrict__ bucket,
                         int* __restrict__ cursor, int n) {
    __shared__ int lcnt[R];
    __shared__ int lbase[R];
    int t = threadIdx.x;
    if (t < R) lcnt[t] = 0;
    __syncthreads();
    int e = blockIdx.x * 256 + t;
    int r = 0, rank = 0;
    if (e < n) {
        r = etype[e];
        rank = atomicAdd(&lcnt[r], 1);
    }
    __syncthreads();
    if (t < R) lbase[t] = atomicAdd(&cursor[t], lcnt[t]);
    __syncthreads();
    if (e < n) bucket[lbase[r] + rank] = e;
}

// ---------- layer 1 shortcut: x = ones -> msg = colsum(W1[r]) ----------
__global__ void k_colsum(const float* __restrict__ w1, float* __restrict__ s1) {
    int idx = blockIdx.x * 256 + threadIdx.x;   // 0..511
    if (idx >= R * D) return;
    int r = idx >> 7, j = idx & (D - 1);
    float s = 0.f;
    for (int k = 0; k < D; ++k) s += w1[((r << 7) + k) * D + j];
    s1[idx] = s;
}

__global__ void k_scatter1(const int* __restrict__ col, const int* __restrict__ etype,
                           const float* __restrict__ coef, const float* __restrict__ s1,
                           float* __restrict__ y, int n /* EN*D */) {
    int idx = blockIdx.x * 256 + threadIdx.x;
    if (idx >= n) return;
    int e = idx >> 7, j = idx & (D - 1);
    float v = coef[e];
    if (v != 0.f)
        atomicAdd(&y[(size_t)col[e] * D + j], v * s1[(etype[e] << 7) + j]);
}

// ---------- post: z = leaky(y + b); feed next layer; accumulate output ----------
__global__ void k_post(const float* __restrict__ y, const float* __restrict__ bias,
                       float* __restrict__ xnext, float* __restrict__ dout,
                       int mode, int n4 /* EN*D/4 */) {
    int idx = blockIdx.x * 256 + threadIdx.x;
    if (idx >= n4) return;
    float4 v = ((const float4*)y)[idx];
    float4 b = ((const float4*)bias)[idx & 31];
    v.x += b.x; v.y += b.y; v.z += b.z; v.w += b.w;
    v.x = (v.x > 0.f) ? v.x : NEG * v.x;
    v.y = (v.y > 0.f) ? v.y : NEG * v.y;
    v.z = (v.z > 0.f) ? v.z : NEG * v.z;
    v.w = (v.w > 0.f) ? v.w : NEG * v.w;
    if (mode == 1) {
        ((float4*)xnext)[idx] = v;
        ((float4*)dout)[idx] = v;
    } else if (mode == 2) {
        ((float4*)xnext)[idx] = v;
        float4 d = ((float4*)dout)[idx];
        d.x += v.x; d.y += v.y; d.z += v.z; d.w += v.w;
        ((float4*)dout)[idx] = d;
    } else {
        float4 d = ((float4*)dout)[idx];
        d.x = (d.x + v.x + 1.f) * 0.25f;
        d.y = (d.y + v.y + 1.f) * 0.25f;
        d.z = (d.z + v.z + 1.f) * 0.25f;
        d.w = (d.w + v.w + 1.f) * 0.25f;
        ((float4*)dout)[idx] = d;
    }
}

// ---------- bucketed fp32 GEMM + scatter (layers 2,3) ----------
// Block: 256 threads, one 64-edge tile of relation blockIdx.y.
// LDS: W K-chunk (32x128 = 16 KB) + x-tile [k][e] (128x64 = 32 KB) + meta.
__global__ __launch_bounds__(256, 3)
void k_gemm(const float* __restrict__ xcur, const float* __restrict__ w,
            const int* __restrict__ bucket, const int* __restrict__ cursor,
            const int* __restrict__ row, const int* __restrict__ col,
            const float* __restrict__ coef, float* __restrict__ y) {
    const int r = blockIdx.y;
    const int cnt = cursor[r] - r * EN;
    const int e_base = blockIdx.x * TM;
    if (e_base >= cnt) return;

    __shared__ float ws_w[KC * D];     // 16 KB, [kk][j]
    __shared__ float xs[D * TM];       // 32 KB, [k][e] stride 64
    __shared__ int   s_row[TM];
    __shared__ int   s_col[TM];
    __shared__ float s_coef[TM];

    const int t = threadIdx.x;

    // edge metadata
    if (t < TM) {
        int idx = e_base + t;
        if (idx < cnt) {
            int eid = bucket[r * EN + idx];
            s_row[t] = row[eid];
            s_col[t] = col[eid];
            s_coef[t] = coef[eid];
        } else {
            s_row[t] = 0; s_col[t] = -1; s_coef[t] = 0.f;
        }
    }
    __syncthreads();

    // gather x rows into xs[k][e]; lane pattern: e = t&63 spreads banks (2-way, free)
    {
        int e = t & 63;
        int kq = t >> 6;                       // 0..3
        const float4* src = (const float4*)(xcur + (size_t)s_row[e] * D);
        #pragma unroll
        for (int it = 0; it < 8; ++it) {
            int k4 = it * 4 + kq;              // float4 index 0..31
            float4 v = src[k4];
            int k = k4 * 4;
            xs[(k + 0) * TM + e] = v.x;
            xs[(k + 1) * TM + e] = v.y;
            xs[(k + 2) * TM + e] = v.z;
            xs[(k + 3) * TM + e] = v.w;
        }
    }

    float acc[4][8];
    #pragma unroll
    for (int i = 0; i < 4; ++i)
        #pragma unroll
        for (int j = 0; j < 8; ++j) acc[i][j] = 0.f;

    const int e0 = (t >> 4) * 4;   // edge group: 16 groups x 4 edges
    const int j0 = (t & 15) * 8;   // col group: 16 groups x 8 cols

    for (int kc = 0; kc < D / KC; ++kc) {
        __syncthreads();   // xs ready (kc=0) / ws_w consumed (kc>0)
        {
            const float4* wg = (const float4*)(w + ((size_t)r * D + kc * KC) * D);
            float4* wl = (float4*)ws_w;
            #pragma unroll
            for (int i = 0; i < 4; ++i) wl[t + i * 256] = wg[t + i * 256];
        }
        __syncthreads();
        #pragma unroll 8
        for (int kk = 0; kk < KC; ++kk) {
            int k = kc * KC + kk;
            float4 a4 = *(const float4*)&xs[k * TM + e0];
            float4 b0 = *(const float4*)&ws_w[kk * D + j0];
            float4 b1 = *(const float4*)&ws_w[kk * D + j0 + 4];
            float a[4] = {a4.x, a4.y, a4.z, a4.w};
            float b[8] = {b0.x, b0.y, b0.z, b0.w, b1.x, b1.y, b1.z, b1.w};
            #pragma unroll
            for (int i = 0; i < 4; ++i)
                #pragma unroll
                for (int j = 0; j < 8; ++j)
                    acc[i][j] += a[i] * b[j];
        }
    }

    // scale by coef and scatter-add
    #pragma unroll
    for (int i = 0; i < 4; ++i) {
        int el = e0 + i;
        float v = s_coef[el];
        int c = s_col[el];
        if (c >= 0 && v != 0.f) {
            float* dst = y + (size_t)c * D + j0;
            #pragma unroll
            for (int j = 0; j < 8; ++j)
                atomicAdd(dst + j, acc[i][j] * v);
        }
    }
}

extern "C" void kernel_launch(void* const* d_in, const int* in_sizes, int n_in,
                              void* d_out, int out_size, void* d_ws, size_t ws_size,
                              hipStream_t stream) {
    const int*   eidx = (const int*)d_in[0];     // [2, E]
    const int*   row  = eidx;
    const int*   col  = eidx + EN;
    const int*   etyp = (const int*)d_in[1];
    const float* attr = (const float*)d_in[2];
    const float* w1   = (const float*)d_in[3];
    const float* b1   = (const float*)d_in[4];
    const float* w2   = (const float*)d_in[5];
    const float* b2   = (const float*)d_in[6];
    const float* w3   = (const float*)d_in[7];
    const float* b3   = (const float*)d_in[8];
    float* dout = (float*)d_out;

    // workspace layout
    const size_t SZ = (size_t)EN * D * sizeof(float);   // 102,400,000 B
    char* wsb = (char*)d_ws;
    float* xcur   = (float*)(wsb);
    float* y      = (float*)(wsb + SZ);
    float* dinv   = (float*)(wsb + 2 * SZ);                       // E floats
    float* coef   = (float*)(wsb + 2 * SZ + 800000);              // E floats
    int*   bucket = (int*)  (wsb + 2 * SZ + 1600000);             // 4E ints
    int*   cursor = (int*)  (wsb + 2 * SZ + 4800000);             // 4 ints
    float* s1     = (float*)(wsb + 2 * SZ + 4800256);             // R*D floats

    const int nE   = EN;
    const int nED  = EN * D;
    const int nED4 = EN * D / 4;
    dim3 blk(256);

    // degree -> dinv -> coef
    hipMemsetAsync(dinv, 0, (size_t)nE * sizeof(float), stream);
    k_deg<<<ceil_div(nE, 256), blk, 0, stream>>>(col, dinv, nE);
    k_dinv<<<ceil_div(nE, 256), blk, 0, stream>>>(dinv, nE);
    k_coef<<<ceil_div(nE, 256), blk, 0, stream>>>(row, col, attr, dinv, coef, nE);

    // bucket edges by relation
    k_cursor_init<<<1, 64, 0, stream>>>(cursor);
    k_bucket<<<ceil_div(nE, 256), blk, 0, stream>>>(etyp, bucket, cursor, nE);

    // layer 1 (x = ones): scatter of colsum(W1)
    k_colsum<<<2, blk, 0, stream>>>(w1, s1);
    hipMemsetAsync(y, 0, SZ, stream);
    k_scatter1<<<ceil_div(nED, 256), blk, 0, stream>>>(col, etyp, coef, s1, y, nED);
    k_post<<<ceil_div(nED4, 256), blk, 0, stream>>>(y, b1, xcur, dout, 1, nED4);

    // layer 2
    hipMemsetAsync(y, 0, SZ, stream);
    {
        dim3 g(ceil_div(nE, TM), R);
        k_gemm<<<g, blk, 0, stream>>>(xcur, w2, bucket, cursor, row, col, coef, y);
    }
    k_post<<<ceil_div(nED4, 256), blk, 0, stream>>>(y, b2, xcur, dout, 2, nED4);

    // layer 3
    hipMemsetAsync(y, 0, SZ, stream);
    {
        dim3 g(ceil_div(nE, TM), R);
        k_gemm<<<g, blk, 0, stream>>>(xcur, w3, bucket, cursor, row, col, coef, y);
    }
    k_post<<<ceil_div(nED4, 256), blk, 0, stream>>>(y, b3, xcur, dout, 3, nED4);
}

// Round 2
// 643.212 us; speedup vs baseline: 2.0737x; 2.0737x over previous
//
#include <hip/hip_runtime.h>
#include <math.h>

// Problem constants (match reference)
constexpr int EN = 200000;   // edges == nodes
constexpr int D  = 128;      // embedding dim
constexpr int R  = 4;        // relation types
constexpr float NEG = 0.01f;

// GEMM tiling
constexpr int TM = 64;       // edges per tile
constexpr int KC = 32;       // K-chunk staged in LDS

static inline int ceil_div(int a, int b) { return (a + b - 1) / b; }

// ---------- histogram: col degree (int) + relation counts ----------
__global__ void k_cnt(const int* __restrict__ col, const int* __restrict__ etype,
                      int* __restrict__ cnt, int* __restrict__ rcnt, int n) {
    __shared__ int lr[R];
    int t = threadIdx.x;
    if (t < R) lr[t] = 0;
    __syncthreads();
    int e = blockIdx.x * 256 + t;
    if (e < n) {
        atomicAdd(&cnt[col[e]], 1);
        atomicAdd(&lr[etype[e]], 1);
    }
    __syncthreads();
    if (t < R) atomicAdd(&rcnt[t], lr[t]);
}

// ---------- coef = attr * rsqrt(deg[row]) * rsqrt(deg[col]) ----------
__global__ void k_coef(const int* __restrict__ row, const int* __restrict__ col,
                       const float* __restrict__ attr, const int* __restrict__ cnt,
                       float* __restrict__ coef, int n) {
    int e = blockIdx.x * 256 + threadIdx.x;
    if (e < n) {
        int dr = cnt[row[e]], dc = cnt[col[e]];
        float a = (dr > 0) ? rsqrtf((float)dr) : 0.f;
        float b = (dc > 0) ? rsqrtf((float)dc) : 0.f;
        coef[e] = attr[e] * a * b;
    }
}

// ---------- 3-kernel exclusive scan of cnt -> col_start[0..EN] ----------
__global__ void k_scan1(const int* __restrict__ cnt, int* __restrict__ part, int n) {
    __shared__ int sm[256];
    int t = threadIdx.x;
    int base = blockIdx.x * 1024 + t * 4;
    int s = 0;
    #pragma unroll
    for (int i = 0; i < 4; ++i) { int idx = base + i; if (idx < n) s += cnt[idx]; }
    sm[t] = s; __syncthreads();
    for (int off = 128; off > 0; off >>= 1) {
        if (t < off) sm[t] += sm[t + off];
        __syncthreads();
    }
    if (t == 0) part[blockIdx.x] = sm[0];
}

__global__ void k_scan2(int* __restrict__ part, int nb) {
    __shared__ int sm[256];
    int t = threadIdx.x;
    sm[t] = (t < nb) ? part[t] : 0;
    __syncthreads();
    for (int off = 1; off < 256; off <<= 1) {
        int u = 0;
        if (t >= off) u = sm[t - off];
        __syncthreads();
        sm[t] += u;
        __syncthreads();
    }
    int ex = (t > 0) ? sm[t - 1] : 0;
    if (t < nb) part[t] = ex;
}

__global__ void k_scan3(const int* __restrict__ cnt, const int* __restrict__ part,
                        int* __restrict__ col_start, int n) {
    __shared__ int sm[256];
    int t = threadIdx.x;
    int base = blockIdx.x * 1024 + t * 4;
    int v[4]; int s = 0;
    #pragma unroll
    for (int i = 0; i < 4; ++i) { int idx = base + i; v[i] = (idx < n) ? cnt[idx] : 0; s += v[i]; }
    sm[t] = s; __syncthreads();
    for (int off = 1; off < 256; off <<= 1) {
        int u = 0;
        if (t >= off) u = sm[t - off];
        __syncthreads();
        sm[t] += u;
        __syncthreads();
    }
    int ex = ((t > 0) ? sm[t - 1] : 0) + part[blockIdx.x];
    #pragma unroll
    for (int i = 0; i < 4; ++i) {
        int idx = base + i;
        if (idx < n) { col_start[idx] = ex; ex += v[i]; }
    }
}

// ---------- tiny: relation-base scan + cursor init + col_start[EN] ----------
__global__ void k_rscan(const int* __restrict__ rcnt, int* __restrict__ rbase,
                        int* __restrict__ cursor, int* __restrict__ col_start) {
    int s = 0;
    for (int r = 0; r < R; ++r) { rbase[r] = s; cursor[r] = s; s += rcnt[r]; }
    rbase[R] = s;
    col_start[EN] = EN;   // total edges
}

// ---------- bucket by relation (compact) + col-sorted placement ----------
__global__ void k_bucket(const int* __restrict__ col, const int* __restrict__ etype,
                         const float* __restrict__ coef, const int* __restrict__ col_start,
                         int* __restrict__ cursor, int* __restrict__ ccur,
                         int* __restrict__ bk_eid, int* __restrict__ sortedpt,
                         float* __restrict__ scoef, int n) {
    __shared__ int lcnt[R];
    __shared__ int lbase[R];
    int t = threadIdx.x;
    if (t < R) lcnt[t] = 0;
    __syncthreads();
    int e = blockIdx.x * 256 + t;
    int r = 0, rank = 0;
    if (e < n) {
        r = etype[e];
        rank = atomicAdd(&lcnt[r], 1);
    }
    __syncthreads();
    if (t < R) lbase[t] = atomicAdd(&cursor[t], lcnt[t]);
    __syncthreads();
    if (e < n) {
        int pos = lbase[r] + rank;            // compact bucket position (msg row)
        bk_eid[pos] = e;
        int c = col[e];
        int sp = col_start[c] + atomicAdd(&ccur[c], 1);
        sortedpt[sp] = (pos << 2) | r;        // packed: msg row + relation
        scoef[sp] = coef[e];
    }
}

// ---------- layer 1 shortcut: s1 = colsum(W1[r]) ----------
__global__ void k_colsum(const float* __restrict__ w1, float* __restrict__ s1) {
    int idx = blockIdx.x * 256 + threadIdx.x;   // 0..511
    if (idx >= R * D) return;
    int r = idx >> 7, j = idx & (D - 1);
    float s = 0.f;
    for (int k = 0; k < D; ++k) s += w1[((r << 7) + k) * D + j];
    s1[idx] = s;
}

// ---------- layer 1 gather: z1 = leaky(sum coef*s1[type] + b1) ----------
__global__ void k_phase1(const float* __restrict__ s1, const float* __restrict__ b1,
                         const int* __restrict__ col_start, const int* __restrict__ sortedpt,
                         const float* __restrict__ scoef,
                         float* __restrict__ xcur, float* __restrict__ dout) {
    __shared__ float ls1[R * D];
    __shared__ float lb[D];
    int t = threadIdx.x;
    ls1[t] = s1[t];
    ls1[t + 256] = s1[t + 256];
    if (t < D) lb[t] = b1[t];
    __syncthreads();
    int lane = t & 63;
    int c = blockIdx.x * 4 + (t >> 6);
    if (c >= EN) return;
    int st = col_start[c], en = col_start[c + 1];
    float a0 = 0.f, a1 = 0.f;
    for (int p = st; p < en; ++p) {
        float cf = scoef[p];
        int tp = sortedpt[p] & 3;
        a0 += cf * ls1[tp * D + lane * 2];
        a1 += cf * ls1[tp * D + lane * 2 + 1];
    }
    a0 += lb[lane * 2]; a1 += lb[lane * 2 + 1];
    a0 = (a0 > 0.f) ? a0 : NEG * a0;
    a1 = (a1 > 0.f) ? a1 : NEG * a1;
    float2 v = {a0, a1};
    ((float2*)(xcur + (size_t)c * D))[lane] = v;
    ((float2*)(dout + (size_t)c * D))[lane] = v;
}

// ---------- bucketed fp32 GEMM -> coalesced msg (no atomics) ----------
__global__ __launch_bounds__(256, 3)
void k_gemm(const float* __restrict__ xcur, const float* __restrict__ w,
            const int* __restrict__ bk_eid, const int* __restrict__ rbase,
            const int* __restrict__ row, const float* __restrict__ coef,
            float* __restrict__ msg) {
    const int r = blockIdx.y;
    const int base = rbase[r];
    const int cnt = rbase[r + 1] - base;
    const int e_base = blockIdx.x * TM;
    if (e_base >= cnt) return;

    __shared__ float ws_w[KC * D];     // 16 KB, [kk][j]
    __shared__ float xs[D * TM];       // 32 KB, [k][e] stride 64
    __shared__ int   s_row[TM];
    __shared__ float s_coef[TM];

    const int t = threadIdx.x;

    if (t < TM) {
        int idx = e_base + t;
        if (idx < cnt) {
            int eid = bk_eid[base + idx];
            s_row[t] = row[eid];
            s_coef[t] = coef[eid];
        } else {
            s_row[t] = 0; s_coef[t] = 0.f;
        }
    }
    __syncthreads();

    // gather x rows into xs[k][e]
    {
        int e = t & 63;
        int kq = t >> 6;                       // 0..3
        const float4* src = (const float4*)(xcur + (size_t)s_row[e] * D);
        #pragma unroll
        for (int it = 0; it < 8; ++it) {
            int k4 = it * 4 + kq;
            float4 v = src[k4];
            int k = k4 * 4;
            xs[(k + 0) * TM + e] = v.x;
            xs[(k + 1) * TM + e] = v.y;
            xs[(k + 2) * TM + e] = v.z;
            xs[(k + 3) * TM + e] = v.w;
        }
    }

    float acc[4][8];
    #pragma unroll
    for (int i = 0; i < 4; ++i)
        #pragma unroll
        for (int j = 0; j < 8; ++j) acc[i][j] = 0.f;

    const int e0 = (t >> 4) * 4;   // edge group
    const int j0 = (t & 15) * 8;   // col group

    for (int kc = 0; kc < D / KC; ++kc) {
        __syncthreads();
        {
            const float4* wg = (const float4*)(w + ((size_t)r * D + kc * KC) * D);
            float4* wl = (float4*)ws_w;
            #pragma unroll
            for (int i = 0; i < 4; ++i) wl[t + i * 256] = wg[t + i * 256];
        }
        __syncthreads();
        #pragma unroll 8
        for (int kk = 0; kk < KC; ++kk) {
            int k = kc * KC + kk;
            float4 a4 = *(const float4*)&xs[k * TM + e0];
            float4 b0 = *(const float4*)&ws_w[kk * D + j0];
            float4 b1 = *(const float4*)&ws_w[kk * D + j0 + 4];
            float a[4] = {a4.x, a4.y, a4.z, a4.w};
            float b[8] = {b0.x, b0.y, b0.z, b0.w, b1.x, b1.y, b1.z, b1.w};
            #pragma unroll
            for (int i = 0; i < 4; ++i)
                #pragma unroll
                for (int j = 0; j < 8; ++j)
                    acc[i][j] += a[i] * b[j];
        }
    }

    // coalesced store: msg[base+e_base+el][j0..j0+7] = coef * acc
    #pragma unroll
    for (int i = 0; i < 4; ++i) {
        int el = e0 + i;
        if (e_base + el < cnt) {
            float v = s_coef[el];
            float* dst = msg + (size_t)(base + e_base + el) * D + j0;
            float4 o0 = {acc[i][0] * v, acc[i][1] * v, acc[i][2] * v, acc[i][3] * v};
            float4 o1 = {acc[i][4] * v, acc[i][5] * v, acc[i][6] * v, acc[i][7] * v};
            ((float4*)dst)[0] = o0;
            ((float4*)dst)[1] = o1;
        }
    }
}

// ---------- gather + bias + leaky + output combine (layers 2,3) ----------
__global__ void k_phaseB(const float* __restrict__ msg, const float* __restrict__ bias,
                         const int* __restrict__ col_start, const int* __restrict__ sortedpt,
                         float* __restrict__ xcur, float* __restrict__ dout, int mode) {
    __shared__ float lb[D];
    int t = threadIdx.x;
    if (t < D) lb[t] = bias[t];
    __syncthreads();
    int lane = t & 63;
    int c = blockIdx.x * 4 + (t >> 6);
    if (c >= EN) return;
    int st = col_start[c], en = col_start[c + 1];
    float a0 = 0.f, a1 = 0.f;
    for (int p = st; p < en; ++p) {
        int bp = sortedpt[p] >> 2;
        float2 m = ((const float2*)(msg + (size_t)bp * D))[lane];
        a0 += m.x; a1 += m.y;
    }
    a0 += lb[lane * 2]; a1 += lb[lane * 2 + 1];
    a0 = (a0 > 0.f) ? a0 : NEG * a0;
    a1 = (a1 > 0.f) ? a1 : NEG * a1;
    float2* xd = (float2*)(xcur + (size_t)c * D);
    float2* dd = (float2*)(dout + (size_t)c * D);
    if (mode == 2) {
        float2 v = {a0, a1};
        xd[lane] = v;
        float2 d = dd[lane];
        d.x += a0; d.y += a1;
        dd[lane] = d;
    } else {
        float2 d = dd[lane];
        d.x = (d.x + a0 + 1.f) * 0.25f;
        d.y = (d.y + a1 + 1.f) * 0.25f;
        dd[lane] = d;
    }
}

extern "C" void kernel_launch(void* const* d_in, const int* in_sizes, int n_in,
                              void* d_out, int out_size, void* d_ws, size_t ws_size,
                              hipStream_t stream) {
    const int*   eidx = (const int*)d_in[0];     // [2, E]
    const int*   row  = eidx;
    const int*   col  = eidx + EN;
    const int*   etyp = (const int*)d_in[1];
    const float* attr = (const float*)d_in[2];
    const float* w1   = (const float*)d_in[3];
    const float* b1   = (const float*)d_in[4];
    const float* w2   = (const float*)d_in[5];
    const float* b2   = (const float*)d_in[6];
    const float* w3   = (const float*)d_in[7];
    const float* b3   = (const float*)d_in[8];
    float* dout = (float*)d_out;

    // workspace layout (~209.6 MB)
    const size_t SZ = (size_t)EN * D * sizeof(float);   // 102,400,000 B
    char* wsb = (char*)d_ws;
    size_t off = 0;
    float* msg      = (float*)(wsb + off); off += SZ;
    float* xcur     = (float*)(wsb + off); off += SZ;
    int*   col_start= (int*)  (wsb + off); off += (size_t)(EN + 1) * 4 + 28; // pad to 8
    int*   cnt      = (int*)  (wsb + off);                       // aliased: cnt then ccur
    int*   ccur     = cnt;                 off += (size_t)EN * 4;
    float* coef     = (float*)(wsb + off); off += (size_t)EN * 4;
    float* scoef    = (float*)(wsb + off); off += (size_t)EN * 4;
    int*   sortedpt = (int*)  (wsb + off); off += (size_t)EN * 4;
    int*   bk_eid   = (int*)  (wsb + off); off += (size_t)EN * 4;
    int*   part     = (int*)  (wsb + off); off += 256 * 4;
    int*   rcnt     = (int*)  (wsb + off); off += 16;
    int*   rbase    = (int*)  (wsb + off); off += 32;
    int*   cursor   = (int*)  (wsb + off); off += 16;
    float* s1       = (float*)(wsb + off); off += (size_t)R * D * 4;

    const int nE = EN;
    const int nBlkE = ceil_div(nE, 256);       // 782
    const int nScan = ceil_div(nE, 1024);      // 196
    dim3 blk(256);

    // histogram (col degrees + relation counts)
    hipMemsetAsync(cnt, 0, (size_t)nE * 4, stream);
    hipMemsetAsync(rcnt, 0, 16, stream);
    k_cnt<<<nBlkE, blk, 0, stream>>>(col, etyp, cnt, rcnt, nE);

    // scan cnt -> col_start
    k_scan1<<<nScan, blk, 0, stream>>>(cnt, part, nE);
    k_scan2<<<1, blk, 0, stream>>>(part, nScan);
    k_scan3<<<nScan, blk, 0, stream>>>(cnt, part, col_start, nE);

    // coef (reads cnt as degree)
    k_coef<<<nBlkE, blk, 0, stream>>>(row, col, attr, cnt, coef, nE);

    // relation bases, then bucket + col-sort placement (cnt region becomes ccur)
    k_rscan<<<1, 1, 0, stream>>>(rcnt, rbase, cursor, col_start);
    hipMemsetAsync(ccur, 0, (size_t)nE * 4, stream);
    k_bucket<<<nBlkE, blk, 0, stream>>>(col, etyp, coef, col_start, cursor, ccur,
                                        bk_eid, sortedpt, scoef, nE);

    // layer 1 (x = ones): column sums of W1, then per-column gather
    k_colsum<<<2, blk, 0, stream>>>(w1, s1);
    k_phase1<<<ceil_div(nE, 4), blk, 0, stream>>>(s1, b1, col_start, sortedpt, scoef,
                                                  xcur, dout);

    // layer 2
    {
        dim3 g(ceil_div(nE, TM), R);
        k_gemm<<<g, blk, 0, stream>>>(xcur, w2, bk_eid, rbase, row, coef, msg);
    }
    k_phaseB<<<ceil_div(nE, 4), blk, 0, stream>>>(msg, b2, col_start, sortedpt,
                                                  xcur, dout, 2);

    // layer 3
    {
        dim3 g(ceil_div(nE, TM), R);
        k_gemm<<<g, blk, 0, stream>>>(xcur, w3, bk_eid, rbase, row, coef, msg);
    }
    k_phaseB<<<ceil_div(nE, 4), blk, 0, stream>>>(msg, b3, col_start, sortedpt,
                                                  xcur, dout, 3);
}

// Round 3
// 607.018 us; speedup vs baseline: 2.1974x; 1.0596x over previous
//
#include <hip/hip_runtime.h>
#include <math.h>

// Problem constants (match reference)
constexpr int EN = 200000;   // edges == nodes
constexpr int D  = 128;      // embedding dim
constexpr int R  = 4;        // relation types
constexpr float NEG = 0.01f;

// GEMM tiling
constexpr int TM = 64;       // edges per tile
constexpr int KC = 32;       // K-chunk staged in LDS

static inline int ceil_div(int a, int b) { return (a + b - 1) / b; }

// ---------- histogram: col degree (int) + relation counts ----------
__global__ void k_cnt(const int* __restrict__ col, const int* __restrict__ etype,
                      int* __restrict__ cnt, int* __restrict__ rcnt, int n) {
    __shared__ int lr[R];
    int t = threadIdx.x;
    if (t < R) lr[t] = 0;
    __syncthreads();
    int e = blockIdx.x * 256 + t;
    if (e < n) {
        atomicAdd(&cnt[col[e]], 1);
        atomicAdd(&lr[etype[e]], 1);
    }
    __syncthreads();
    if (t < R) atomicAdd(&rcnt[t], lr[t]);
}

// ---------- 3-kernel exclusive scan of cnt -> col_start[0..EN] ----------
__global__ void k_scan1(const int* __restrict__ cnt, int* __restrict__ part, int n) {
    __shared__ int sm[256];
    int t = threadIdx.x;
    int base = blockIdx.x * 1024 + t * 4;
    int s = 0;
    #pragma unroll
    for (int i = 0; i < 4; ++i) { int idx = base + i; if (idx < n) s += cnt[idx]; }
    sm[t] = s; __syncthreads();
    for (int off = 128; off > 0; off >>= 1) {
        if (t < off) sm[t] += sm[t + off];
        __syncthreads();
    }
    if (t == 0) part[blockIdx.x] = sm[0];
}

__global__ void k_scan2(int* __restrict__ part, int nb) {
    __shared__ int sm[256];
    int t = threadIdx.x;
    sm[t] = (t < nb) ? part[t] : 0;
    __syncthreads();
    for (int off = 1; off < 256; off <<= 1) {
        int u = 0;
        if (t >= off) u = sm[t - off];
        __syncthreads();
        sm[t] += u;
        __syncthreads();
    }
    int ex = (t > 0) ? sm[t - 1] : 0;
    if (t < nb) part[t] = ex;
}

__global__ void k_scan3(const int* __restrict__ cnt, const int* __restrict__ part,
                        int* __restrict__ col_start, int n) {
    __shared__ int sm[256];
    int t = threadIdx.x;
    int base = blockIdx.x * 1024 + t * 4;
    int v[4]; int s = 0;
    #pragma unroll
    for (int i = 0; i < 4; ++i) { int idx = base + i; v[i] = (idx < n) ? cnt[idx] : 0; s += v[i]; }
    sm[t] = s; __syncthreads();
    for (int off = 1; off < 256; off <<= 1) {
        int u = 0;
        if (t >= off) u = sm[t - off];
        __syncthreads();
        sm[t] += u;
        __syncthreads();
    }
    int ex = ((t > 0) ? sm[t - 1] : 0) + part[blockIdx.x];
    #pragma unroll
    for (int i = 0; i < 4; ++i) {
        int idx = base + i;
        if (idx < n) { col_start[idx] = ex; ex += v[i]; }
    }
}

// ---------- tiny: relation-base scan + cursor init + col_start[EN] ----------
__global__ void k_rscan(const int* __restrict__ rcnt, int* __restrict__ rbase,
                        int* __restrict__ cursor, int* __restrict__ col_start) {
    int s = 0;
    for (int r = 0; r < R; ++r) { rbase[r] = s; cursor[r] = s; s += rcnt[r]; }
    rbase[R] = s;
    col_start[EN] = EN;   // total edges
}

// ---------- bucket by relation + col-sorted placement + coef ----------
// bk_row[pos]  : source row of bucket-pos edge (GEMM gather)
// bk_dst[pos]  : col-sorted position (GEMM store target = msg row)
// scoef[sp]    : per-edge coefficient in sorted order
// styp[sp]     : relation in sorted order (layer-1 gather)
__global__ void k_bucket(const int* __restrict__ row, const int* __restrict__ col,
                         const int* __restrict__ etype, const float* __restrict__ attr,
                         const int* __restrict__ cnt, const int* __restrict__ col_start,
                         int* __restrict__ cursor, int* __restrict__ ccur,
                         int* __restrict__ bk_row, int* __restrict__ bk_dst,
                         float* __restrict__ scoef, unsigned char* __restrict__ styp,
                         int n) {
    __shared__ int lcnt[R];
    __shared__ int lbase[R];
    int t = threadIdx.x;
    if (t < R) lcnt[t] = 0;
    __syncthreads();
    int e = blockIdx.x * 256 + t;
    int r = 0, rank = 0, c = 0, rw = 0;
    float cf = 0.f;
    if (e < n) {
        r = etype[e];
        rank = atomicAdd(&lcnt[r], 1);
        c = col[e]; rw = row[e];
        int dr = cnt[rw], dc = cnt[c];
        float a = (dr > 0) ? rsqrtf((float)dr) : 0.f;
        float b = (dc > 0) ? rsqrtf((float)dc) : 0.f;
        cf = attr[e] * a * b;
    }
    __syncthreads();
    if (t < R) lbase[t] = atomicAdd(&cursor[t], lcnt[t]);
    __syncthreads();
    if (e < n) {
        int pos = lbase[r] + rank;                     // relation-bucket position
        int sp = col_start[c] + atomicAdd(&ccur[c], 1); // col-sorted position
        bk_row[pos] = rw;
        bk_dst[pos] = sp;
        scoef[sp] = cf;
        styp[sp] = (unsigned char)r;
    }
}

// ---------- layer 1 shortcut: s1 = colsum(W1[r]) ----------
__global__ void k_colsum(const float* __restrict__ w1, float* __restrict__ s1) {
    int idx = blockIdx.x * 256 + threadIdx.x;   // 0..511
    if (idx >= R * D) return;
    int r = idx >> 7, j = idx & (D - 1);
    float s = 0.f;
    for (int k = 0; k < D; ++k) s += w1[((r << 7) + k) * D + j];
    s1[idx] = s;
}

// ---------- layer 1 gather: xcur = z1 = leaky(sum coef*s1[type] + b1) ----------
__global__ void k_phase1(const float* __restrict__ s1, const float* __restrict__ b1,
                         const int* __restrict__ col_start,
                         const unsigned char* __restrict__ styp,
                         const float* __restrict__ scoef,
                         float* __restrict__ xcur) {
    __shared__ float ls1[R * D];
    __shared__ float lb[D];
    int t = threadIdx.x;
    ls1[t] = s1[t];
    ls1[t + 256] = s1[t + 256];
    if (t < D) lb[t] = b1[t];
    __syncthreads();
    int lane = t & 63;
    int c = blockIdx.x * 4 + (t >> 6);
    if (c >= EN) return;
    int st = col_start[c], en = col_start[c + 1];
    float a0 = 0.f, a1 = 0.f;
    for (int p = st; p < en; ++p) {
        float cf = scoef[p];
        int tp = styp[p];
        a0 += cf * ls1[tp * D + lane * 2];
        a1 += cf * ls1[tp * D + lane * 2 + 1];
    }
    a0 += lb[lane * 2]; a1 += lb[lane * 2 + 1];
    a0 = (a0 > 0.f) ? a0 : NEG * a0;
    a1 = (a1 > 0.f) ? a1 : NEG * a1;
    float2 v = {a0, a1};
    ((float2*)(xcur + (size_t)c * D))[lane] = v;
}

// ---------- bucketed fp32 GEMM -> col-sorted msg (no atomics) ----------
// Staging: 8 full rows per wave-instruction (coalesced 512 B), XOR-swizzled
// float4 LDS layout xs4[kq*64 + (e^kq)] = x[e][4kq..4kq+3] (min-round read+write).
__global__ __launch_bounds__(256, 3)
void k_gemm(const float* __restrict__ xcur, const float* __restrict__ w,
            const int* __restrict__ bk_row, const int* __restrict__ bk_dst,
            const float* __restrict__ scoef, const int* __restrict__ rbase,
            float* __restrict__ msg) {
    const int r = blockIdx.y;
    const int base = rbase[r];
    const int cnt = rbase[r + 1] - base;
    const int e_base = blockIdx.x * TM;
    if (e_base >= cnt) return;

    __shared__ float  ws_w[KC * D];    // 16 KB [kk][j]
    __shared__ float4 xs4[32 * TM];    // 32 KB swizzled
    __shared__ int    s_row[TM];
    __shared__ int    s_dst[TM];
    __shared__ float  s_coef[TM];

    const int t = threadIdx.x;

    if (t < TM) {
        int idx = e_base + t;
        if (idx < cnt) {
            int p = base + idx;
            s_row[t] = bk_row[p];
            int dp = bk_dst[p];
            s_dst[t] = dp;
            s_coef[t] = scoef[dp];
        } else {
            s_row[t] = 0; s_dst[t] = -1; s_coef[t] = 0.f;
        }
    }
    __syncthreads();

    // stage x rows: it 0..7, 8 rows per 256-thread round, full-row coalesced
    {
        int s = t & 31;          // float4 index within row
        int h = t >> 5;          // 0..7
        #pragma unroll
        for (int it = 0; it < 8; ++it) {
            int e = it * 8 + h;
            float4 v = ((const float4*)(xcur + (size_t)s_row[e] * D))[s];
            xs4[s * TM + (e ^ s)] = v;
        }
    }

    float acc[4][8];
    #pragma unroll
    for (int i = 0; i < 4; ++i)
        #pragma unroll
        for (int j = 0; j < 8; ++j) acc[i][j] = 0.f;

    const int e0 = (t >> 4) * 4;   // edge group
    const int jq = (t & 15);       // cols jq*4..+3 and 64+jq*4..+3

    for (int kc = 0; kc < D / KC; ++kc) {
        __syncthreads();
        {
            const float4* wg = (const float4*)(w + ((size_t)r * D + kc * KC) * D);
            float4* wl = (float4*)ws_w;
            #pragma unroll
            for (int i = 0; i < 4; ++i) wl[t + i * 256] = wg[t + i * 256];
        }
        __syncthreads();
        #pragma unroll
        for (int kq8 = 0; kq8 < KC / 4; ++kq8) {
            int kq = kc * (KC / 4) + kq8;     // global k-quad 0..31
            float4 av[4];
            #pragma unroll
            for (int i = 0; i < 4; ++i)
                av[i] = xs4[kq * TM + ((e0 + i) ^ kq)];
            #pragma unroll
            for (int k4 = 0; k4 < 4; ++k4) {
                int kk = kq8 * 4 + k4;
                float4 b0 = *(const float4*)&ws_w[kk * D + jq * 4];
                float4 b1 = *(const float4*)&ws_w[kk * D + 64 + jq * 4];
                float a[4] = { ((const float*)&av[0])[k4], ((const float*)&av[1])[k4],
                               ((const float*)&av[2])[k4], ((const float*)&av[3])[k4] };
                float b[8] = {b0.x, b0.y, b0.z, b0.w, b1.x, b1.y, b1.z, b1.w};
                #pragma unroll
                for (int i = 0; i < 4; ++i)
                    #pragma unroll
                    for (int j = 0; j < 8; ++j)
                        acc[i][j] += a[i] * b[j];
            }
        }
    }

    // store: msg row = col-sorted position (random row, contiguous 512 B)
    #pragma unroll
    for (int i = 0; i < 4; ++i) {
        int el = e0 + i;
        int dp = s_dst[el];
        if (dp >= 0) {
            float v = s_coef[el];
            float* dst = msg + (size_t)dp * D;
            float4 o0 = {acc[i][0] * v, acc[i][1] * v, acc[i][2] * v, acc[i][3] * v};
            float4 o1 = {acc[i][4] * v, acc[i][5] * v, acc[i][6] * v, acc[i][7] * v};
            *(float4*)(dst + jq * 4) = o0;
            *(float4*)(dst + 64 + jq * 4) = o1;
        }
    }
}

// ---------- sequential gather + bias + leaky + combine (layers 2,3) ----------
// mode 2: reads xcur (=z1), writes xcur=z2 and dout=z1+z2
// mode 3: dout = (dout + z3 + 1) * 0.25
__global__ void k_phaseB(const float* __restrict__ msg, const float* __restrict__ bias,
                         const int* __restrict__ col_start,
                         float* __restrict__ xcur, float* __restrict__ dout, int mode) {
    __shared__ float lb[D];
    int t = threadIdx.x;
    if (t < D) lb[t] = bias[t];
    __syncthreads();
    int lane = t & 63;
    int c = blockIdx.x * 4 + (t >> 6);
    if (c >= EN) return;
    int st = col_start[c], en = col_start[c + 1];
    float a0 = 0.f, a1 = 0.f;
    const float2* mp = (const float2*)msg;
    for (int p = st; p < en; ++p) {
        float2 m = mp[(size_t)p * 64 + lane];
        a0 += m.x; a1 += m.y;
    }
    a0 += lb[lane * 2]; a1 += lb[lane * 2 + 1];
    a0 = (a0 > 0.f) ? a0 : NEG * a0;
    a1 = (a1 > 0.f) ? a1 : NEG * a1;
    float2* xd = (float2*)(xcur + (size_t)c * D);
    float2* dd = (float2*)(dout + (size_t)c * D);
    if (mode == 2) {
        float2 z1 = xd[lane];
        float2 v = {a0, a1};
        xd[lane] = v;
        float2 s = {z1.x + a0, z1.y + a1};
        dd[lane] = s;
    } else {
        float2 d = dd[lane];
        d.x = (d.x + a0 + 1.f) * 0.25f;
        d.y = (d.y + a1 + 1.f) * 0.25f;
        dd[lane] = d;
    }
}

extern "C" void kernel_launch(void* const* d_in, const int* in_sizes, int n_in,
                              void* d_out, int out_size, void* d_ws, size_t ws_size,
                              hipStream_t stream) {
    const int*   eidx = (const int*)d_in[0];     // [2, E]
    const int*   row  = eidx;
    const int*   col  = eidx + EN;
    const int*   etyp = (const int*)d_in[1];
    const float* attr = (const float*)d_in[2];
    const float* w1   = (const float*)d_in[3];
    const float* b1   = (const float*)d_in[4];
    const float* w2   = (const float*)d_in[5];
    const float* b2   = (const float*)d_in[6];
    const float* w3   = (const float*)d_in[7];
    const float* b3   = (const float*)d_in[8];
    float* dout = (float*)d_out;

    // workspace layout (~209.0 MB; fits the >=209.6 MB ws proven in R1/R2)
    const size_t SZ = (size_t)EN * D * sizeof(float);   // 102,400,000 B
    char* wsb = (char*)d_ws;
    size_t off = 0;
    float* msg      = (float*)(wsb + off); off += SZ;
    float* xcur     = (float*)(wsb + off); off += SZ;
    int*   col_start= (int*)  (wsb + off); off += 800032;          // (EN+1)*4 padded
    int*   cnt      = (int*)  (wsb + off); off += (size_t)EN * 4;
    float* scoef    = (float*)(wsb + off); off += (size_t)EN * 4;
    int*   bk_row   = (int*)  (wsb + off); off += (size_t)EN * 4;
    int*   bk_dst   = (int*)  (wsb + off); off += (size_t)EN * 4;
    unsigned char* styp = (unsigned char*)(wsb + off); off += 200064;
    int*   part     = (int*)  (wsb + off); off += 1024;
    int*   rcnt     = (int*)  (wsb + off); off += 16;
    int*   rbase    = (int*)  (wsb + off); off += 32;
    int*   cursor   = (int*)  (wsb + off); off += 16;
    float* s1       = (float*)(wsb + off); off += (size_t)R * D * 4;
    int*   ccur     = (int*)msg;   // aliased: msg not live until GEMM2

    const int nE = EN;
    const int nBlkE = ceil_div(nE, 256);       // 782
    const int nScan = ceil_div(nE, 1024);      // 196
    dim3 blk(256);

    // histogram (col degrees + relation counts)
    hipMemsetAsync(cnt, 0, (size_t)nE * 4, stream);
    hipMemsetAsync(rcnt, 0, 16, stream);
    k_cnt<<<nBlkE, blk, 0, stream>>>(col, etyp, cnt, rcnt, nE);

    // scan cnt -> col_start
    k_scan1<<<nScan, blk, 0, stream>>>(cnt, part, nE);
    k_scan2<<<1, blk, 0, stream>>>(part, nScan);
    k_scan3<<<nScan, blk, 0, stream>>>(cnt, part, col_start, nE);

    // relation bases; then bucket + col-sort placement (+ inline coef)
    k_rscan<<<1, 1, 0, stream>>>(rcnt, rbase, cursor, col_start);
    hipMemsetAsync(ccur, 0, (size_t)nE * 4, stream);
    k_bucket<<<nBlkE, blk, 0, stream>>>(row, col, etyp, attr, cnt, col_start,
                                        cursor, ccur, bk_row, bk_dst, scoef, styp, nE);

    // layer 1 (x = ones): column sums of W1, then per-column gather -> xcur=z1
    k_colsum<<<2, blk, 0, stream>>>(w1, s1);
    k_phase1<<<ceil_div(nE, 4), blk, 0, stream>>>(s1, b1, col_start, styp, scoef, xcur);

    // layer 2
    {
        dim3 g(ceil_div(nE, TM), R);
        k_gemm<<<g, blk, 0, stream>>>(xcur, w2, bk_row, bk_dst, scoef, rbase, msg);
    }
    k_phaseB<<<ceil_div(nE, 4), blk, 0, stream>>>(msg, b2, col_start, xcur, dout, 2);

    // layer 3
    {
        dim3 g(ceil_div(nE, TM), R);
        k_gemm<<<g, blk, 0, stream>>>(xcur, w3, bk_row, bk_dst, scoef, rbase, msg);
    }
    k_phaseB<<<ceil_div(nE, 4), blk, 0, stream>>>(msg, b3, col_start, xcur, dout, 3);
}

// Round 4
// 386.235 us; speedup vs baseline: 3.4534x; 1.5716x over previous
//
#include <hip/hip_runtime.h>
#include <math.h>

// Problem constants (match reference)
constexpr int EN = 200000;   // edges == nodes
constexpr int D  = 128;      // embedding dim
constexpr int R  = 4;        // relation types
constexpr float NEG = 0.01f;

static inline int ceil_div(int a, int b) { return (a + b - 1) / b; }

typedef __attribute__((ext_vector_type(8))) __bf16 bf16x8;
typedef __attribute__((ext_vector_type(4))) float f32x4;

// ---------- bf16 helpers (RNE) ----------
__device__ __forceinline__ unsigned short f2bf(float f) {
    union { float f; unsigned u; } v; v.f = f;
    unsigned u = v.u + 0x7fffu + ((v.u >> 16) & 1u);
    return (unsigned short)(u >> 16);
}
__device__ __forceinline__ unsigned pack2bf(float a, float b) {
    return (unsigned)f2bf(a) | ((unsigned)f2bf(b) << 16);
}
__device__ __forceinline__ float bflo(unsigned m) { return __uint_as_float(m << 16); }
__device__ __forceinline__ float bfhi(unsigned m) { return __uint_as_float(m & 0xffff0000u); }

// ---------- histogram: col degree (int) + relation counts ----------
__global__ void k_cnt(const int* __restrict__ col, const int* __restrict__ etype,
                      int* __restrict__ cnt, int* __restrict__ rcnt, int n) {
    __shared__ int lr[R];
    int t = threadIdx.x;
    if (t < R) lr[t] = 0;
    __syncthreads();
    int e = blockIdx.x * 256 + t;
    if (e < n) {
        atomicAdd(&cnt[col[e]], 1);
        atomicAdd(&lr[etype[e]], 1);
    }
    __syncthreads();
    if (t < R) atomicAdd(&rcnt[t], lr[t]);
}

// ---------- 3-kernel exclusive scan of cnt -> col_start[0..EN] ----------
__global__ void k_scan1(const int* __restrict__ cnt, int* __restrict__ part, int n) {
    __shared__ int sm[256];
    int t = threadIdx.x;
    int base = blockIdx.x * 1024 + t * 4;
    int s = 0;
    #pragma unroll
    for (int i = 0; i < 4; ++i) { int idx = base + i; if (idx < n) s += cnt[idx]; }
    sm[t] = s; __syncthreads();
    for (int off = 128; off > 0; off >>= 1) {
        if (t < off) sm[t] += sm[t + off];
        __syncthreads();
    }
    if (t == 0) part[blockIdx.x] = sm[0];
}

__global__ void k_scan2(int* __restrict__ part, int nb) {
    __shared__ int sm[256];
    int t = threadIdx.x;
    sm[t] = (t < nb) ? part[t] : 0;
    __syncthreads();
    for (int off = 1; off < 256; off <<= 1) {
        int u = 0;
        if (t >= off) u = sm[t - off];
        __syncthreads();
        sm[t] += u;
        __syncthreads();
    }
    int ex = (t > 0) ? sm[t - 1] : 0;
    if (t < nb) part[t] = ex;
}

__global__ void k_scan3(const int* __restrict__ cnt, const int* __restrict__ part,
                        int* __restrict__ col_start, int n) {
    __shared__ int sm[256];
    int t = threadIdx.x;
    int base = blockIdx.x * 1024 + t * 4;
    int v[4]; int s = 0;
    #pragma unroll
    for (int i = 0; i < 4; ++i) { int idx = base + i; v[i] = (idx < n) ? cnt[idx] : 0; s += v[i]; }
    sm[t] = s; __syncthreads();
    for (int off = 1; off < 256; off <<= 1) {
        int u = 0;
        if (t >= off) u = sm[t - off];
        __syncthreads();
        sm[t] += u;
        __syncthreads();
    }
    int ex = ((t > 0) ? sm[t - 1] : 0) + part[blockIdx.x];
    #pragma unroll
    for (int i = 0; i < 4; ++i) {
        int idx = base + i;
        if (idx < n) { col_start[idx] = ex; ex += v[i]; }
    }
}

// ---------- tiny: relation-base scan + cursor init + col_start[EN] ----------
__global__ void k_rscan(const int* __restrict__ rcnt, int* __restrict__ rbase,
                        int* __restrict__ cursor, int* __restrict__ col_start) {
    int s = 0;
    for (int r = 0; r < R; ++r) { rbase[r] = s; cursor[r] = s; s += rcnt[r]; }
    rbase[R] = s;
    col_start[EN] = EN;
}

// ---------- bucket by relation + col-sorted placement + coef ----------
__global__ void k_bucket(const int* __restrict__ row, const int* __restrict__ col,
                         const int* __restrict__ etype, const float* __restrict__ attr,
                         const int* __restrict__ cnt, const int* __restrict__ col_start,
                         int* __restrict__ cursor, int* __restrict__ ccur,
                         int* __restrict__ bk_row, int* __restrict__ bk_dst,
                         float* __restrict__ bk_coef,
                         float* __restrict__ scoef, unsigned char* __restrict__ styp,
                         int n) {
    __shared__ int lcnt[R];
    __shared__ int lbase[R];
    int t = threadIdx.x;
    if (t < R) lcnt[t] = 0;
    __syncthreads();
    int e = blockIdx.x * 256 + t;
    int r = 0, rank = 0, c = 0, rw = 0;
    float cf = 0.f;
    if (e < n) {
        r = etype[e];
        rank = atomicAdd(&lcnt[r], 1);
        c = col[e]; rw = row[e];
        int dr = cnt[rw], dc = cnt[c];
        float a = (dr > 0) ? rsqrtf((float)dr) : 0.f;
        float b = (dc > 0) ? rsqrtf((float)dc) : 0.f;
        cf = attr[e] * a * b;
    }
    __syncthreads();
    if (t < R) lbase[t] = atomicAdd(&cursor[t], lcnt[t]);
    __syncthreads();
    if (e < n) {
        int pos = lbase[r] + rank;                       // relation-bucket position
        int sp = col_start[c] + atomicAdd(&ccur[c], 1);  // col-sorted position
        bk_row[pos] = rw;
        bk_dst[pos] = sp;
        bk_coef[pos] = cf;
        scoef[sp] = cf;
        styp[sp] = (unsigned char)r;
    }
}

// ---------- pre-swizzle W (fp32 row-major K x N per relation) -> MFMA A-frag bf16 ----------
// out[((r*4 + s)*8 + mt)*64 + lane][j] = bf16( w[r][k = s*32 + (lane>>4)*8 + j][n = mt*16 + (lane&15)] )
__global__ void k_wswz(const float* __restrict__ w, unsigned short* __restrict__ wsw) {
    int t = blockIdx.x * 256 + threadIdx.x;   // 0..8191
    if (t >= R * 4 * 8 * 64) return;
    int lane = t & 63, mt = (t >> 6) & 7, s = (t >> 9) & 3, r = t >> 11;
    int q = lane >> 4, n = mt * 16 + (lane & 15);
    union { unsigned short us[8]; uint4 u4; } o;
    #pragma unroll
    for (int j = 0; j < 8; ++j) {
        int k = s * 32 + q * 8 + j;
        o.us[j] = f2bf(w[((size_t)r * D + k) * D + n]);
    }
    *(uint4*)(wsw + (size_t)t * 8) = o.u4;
}

// ---------- layer 1 shortcut: s1 = colsum(W1[r]) ----------
__global__ void k_colsum(const float* __restrict__ w1, float* __restrict__ s1) {
    int idx = blockIdx.x * 256 + threadIdx.x;
    if (idx >= R * D) return;
    int r = idx >> 7, j = idx & (D - 1);
    float s = 0.f;
    for (int k = 0; k < D; ++k) s += w1[((r << 7) + k) * D + j];
    s1[idx] = s;
}

// ---------- layer 1 gather: xb = bf16(z1) ----------
__global__ void k_phase1(const float* __restrict__ s1, const float* __restrict__ b1,
                         const int* __restrict__ col_start,
                         const unsigned char* __restrict__ styp,
                         const float* __restrict__ scoef,
                         unsigned* __restrict__ xb32) {
    __shared__ float ls1[R * D];
    __shared__ float lb[D];
    int t = threadIdx.x;
    ls1[t] = s1[t];
    ls1[t + 256] = s1[t + 256];
    if (t < D) lb[t] = b1[t];
    __syncthreads();
    int lane = t & 63;
    int c = blockIdx.x * 4 + (t >> 6);
    if (c >= EN) return;
    int st = col_start[c], en = col_start[c + 1];
    float a0 = 0.f, a1 = 0.f;
    for (int p = st; p < en; ++p) {
        float cf = scoef[p];
        int tp = styp[p];
        a0 += cf * ls1[tp * D + lane * 2];
        a1 += cf * ls1[tp * D + lane * 2 + 1];
    }
    a0 += lb[lane * 2]; a1 += lb[lane * 2 + 1];
    a0 = (a0 > 0.f) ? a0 : NEG * a0;
    a1 = (a1 > 0.f) ? a1 : NEG * a1;
    xb32[(size_t)c * 64 + lane] = pack2bf(a0, a1);
}

// ---------- MFMA GEMM: one wave per 16-edge tile, no LDS, no barriers ----------
// D^T = W^T (A-operand, pre-swizzled) x x^T (B-operand, row gather).
// Lane l: edge = tile*16 + (l&15), holds output cols n = mt*16 + (l>>4)*4 + reg.
__global__ __launch_bounds__(256)
void k_gemm(const unsigned short* __restrict__ xb, const unsigned short* __restrict__ wsw,
            const int* __restrict__ bk_row, const int* __restrict__ bk_dst,
            const float* __restrict__ bk_coef, const int* __restrict__ rbase,
            unsigned short* __restrict__ msgb) {
    const int r = blockIdx.y;
    const int base = rbase[r];
    const int cnt = rbase[r + 1] - base;
    const int t = threadIdx.x;
    const int tile = blockIdx.x * 4 + (t >> 6);
    if (tile * 16 >= cnt) return;           // wave-uniform early exit
    const int l = t & 63, q = l >> 4, n16 = l & 15;
    const int eidx = tile * 16 + n16;
    const bool valid = eidx < cnt;
    const int p = base + eidx;              // < EN + 16 (arrays padded by 64)
    const int srow = bk_row[p];
    const int dp = bk_dst[p];
    const float cf = bk_coef[p];

    // B-frags: x[edge][k], 16 B per lane per K-step
    const unsigned short* xrow = xb + (size_t)srow * D;
    bf16x8 xf[4];
    #pragma unroll
    for (int s = 0; s < 4; ++s)
        xf[s] = *(const bf16x8*)(xrow + s * 32 + q * 8);

    // A-frags: swizzled W, L1/L2-resident
    const unsigned short* wr = wsw + ((size_t)r * 2048 + l) * 8;

    f32x4 acc[8];
    #pragma unroll
    for (int mt = 0; mt < 8; ++mt) acc[mt] = (f32x4){0.f, 0.f, 0.f, 0.f};

    #pragma unroll
    for (int s = 0; s < 4; ++s) {
        #pragma unroll
        for (int mt = 0; mt < 8; ++mt) {
            bf16x8 wf = *(const bf16x8*)(wr + (size_t)(s * 512 + mt * 64) * 8);
            acc[mt] = __builtin_amdgcn_mfma_f32_16x16x32_bf16(wf, xf[s], acc[mt], 0, 0, 0);
        }
    }

    // epilogue: scale by coef, pack 4 consecutive cols to 8 B, store
    const float c = valid ? cf : 0.f;
    unsigned short* dst = msgb + (size_t)(valid ? dp : EN) * D + q * 4;
    #pragma unroll
    for (int mt = 0; mt < 8; ++mt) {
        uint2 u;
        u.x = pack2bf(acc[mt].x * c, acc[mt].y * c);
        u.y = pack2bf(acc[mt].z * c, acc[mt].w * c);
        *(uint2*)(dst + mt * 16) = u;
    }
}

// ---------- sequential gather + bias + leaky + combine (layers 2,3) ----------
// mode 2: z1 = xb; xb = z2 (bf16); zsum = z1+z2 (bf16)
// mode 3: dout = (1 + zsum + z3) * 0.25 (fp32)
__global__ void k_phaseB(const unsigned* __restrict__ msgb32, const float* __restrict__ bias,
                         const int* __restrict__ col_start,
                         unsigned* __restrict__ xb32, unsigned* __restrict__ zs32,
                         float* __restrict__ dout, int mode) {
    __shared__ float lb[D];
    int t = threadIdx.x;
    if (t < D) lb[t] = bias[t];
    __syncthreads();
    int lane = t & 63;
    int c = blockIdx.x * 4 + (t >> 6);
    if (c >= EN) return;
    int st = col_start[c], en = col_start[c + 1];
    float a0 = 0.f, a1 = 0.f;
    for (int p = st; p < en; ++p) {
        unsigned m = msgb32[(size_t)p * 64 + lane];
        a0 += bflo(m); a1 += bfhi(m);
    }
    a0 += lb[lane * 2]; a1 += lb[lane * 2 + 1];
    a0 = (a0 > 0.f) ? a0 : NEG * a0;
    a1 = (a1 > 0.f) ? a1 : NEG * a1;
    size_t ix = (size_t)c * 64 + lane;
    if (mode == 2) {
        unsigned z1 = xb32[ix];
        xb32[ix] = pack2bf(a0, a1);
        zs32[ix] = pack2bf(bflo(z1) + a0, bfhi(z1) + a1);
    } else {
        unsigned zs = zs32[ix];
        float2 o;
        o.x = (1.f + bflo(zs) + a0) * 0.25f;
        o.y = (1.f + bfhi(zs) + a1) * 0.25f;
        ((float2*)(dout + (size_t)c * D))[lane] = o;
    }
}

extern "C" void kernel_launch(void* const* d_in, const int* in_sizes, int n_in,
                              void* d_out, int out_size, void* d_ws, size_t ws_size,
                              hipStream_t stream) {
    const int*   eidx = (const int*)d_in[0];     // [2, E]
    const int*   row  = eidx;
    const int*   col  = eidx + EN;
    const int*   etyp = (const int*)d_in[1];
    const float* attr = (const float*)d_in[2];
    const float* w1   = (const float*)d_in[3];
    const float* b1   = (const float*)d_in[4];
    const float* w2   = (const float*)d_in[5];
    const float* b2   = (const float*)d_in[6];
    const float* w3   = (const float*)d_in[7];
    const float* b3   = (const float*)d_in[8];
    float* dout = (float*)d_out;

    // workspace layout (~160 MB, under the >=209 MB proven in R2/R3)
    char* wsb = (char*)d_ws;
    size_t off = 0;
    unsigned short* msgb = (unsigned short*)(wsb + off); off += (size_t)(EN + 1) * D * 2 + 512;  // bf16, +dump row
    unsigned short* xb   = (unsigned short*)(wsb + off); off += (size_t)EN * D * 2;              // bf16
    unsigned short* zsb  = (unsigned short*)(wsb + off); off += (size_t)EN * D * 2;              // bf16
    int*   col_start = (int*)(wsb + off); off += 800032;
    int*   cnt       = (int*)(wsb + off); off += (size_t)EN * 4;
    float* scoef     = (float*)(wsb + off); off += (size_t)EN * 4;
    unsigned char* styp = (unsigned char*)(wsb + off); off += 200064;
    int*   bk_row    = (int*)(wsb + off); off += (size_t)(EN + 64) * 4;
    int*   bk_dst    = (int*)(wsb + off); off += (size_t)(EN + 64) * 4;
    float* bk_coef   = (float*)(wsb + off); off += (size_t)(EN + 64) * 4;
    unsigned short* w2b = (unsigned short*)(wsb + off); off += 131072;
    unsigned short* w3b = (unsigned short*)(wsb + off); off += 131072;
    int*   part      = (int*)(wsb + off); off += 1024;
    int*   rcnt      = (int*)(wsb + off); off += 16;
    int*   rbase     = (int*)(wsb + off); off += 32;
    int*   cursor    = (int*)(wsb + off); off += 16;
    float* s1        = (float*)(wsb + off); off += (size_t)R * D * 4;
    int*   ccur      = (int*)msgb;   // aliased: msgb not live until GEMM2

    const int nE = EN;
    const int nBlkE = ceil_div(nE, 256);
    const int nScan = ceil_div(nE, 1024);
    dim3 blk(256);

    // histogram
    hipMemsetAsync(cnt, 0, (size_t)nE * 4, stream);
    hipMemsetAsync(rcnt, 0, 16, stream);
    hipMemsetAsync(bk_row + EN, 0, 64 * 4, stream);   // pad: safe gather row
    k_cnt<<<nBlkE, blk, 0, stream>>>(col, etyp, cnt, rcnt, nE);

    // scan cnt -> col_start
    k_scan1<<<nScan, blk, 0, stream>>>(cnt, part, nE);
    k_scan2<<<1, blk, 0, stream>>>(part, nScan);
    k_scan3<<<nScan, blk, 0, stream>>>(cnt, part, col_start, nE);

    // relation bases; bucket + col-sort placement (+ coef)
    k_rscan<<<1, 1, 0, stream>>>(rcnt, rbase, cursor, col_start);
    hipMemsetAsync(ccur, 0, (size_t)nE * 4, stream);
    k_bucket<<<nBlkE, blk, 0, stream>>>(row, col, etyp, attr, cnt, col_start,
                                        cursor, ccur, bk_row, bk_dst, bk_coef,
                                        scoef, styp, nE);

    // weight pre-swizzle (bf16 A-frag layout)
    k_wswz<<<32, blk, 0, stream>>>(w2, w2b);
    k_wswz<<<32, blk, 0, stream>>>(w3, w3b);

    // layer 1 (x = ones)
    k_colsum<<<2, blk, 0, stream>>>(w1, s1);
    k_phase1<<<ceil_div(nE, 4), blk, 0, stream>>>(s1, b1, col_start, styp, scoef,
                                                  (unsigned*)xb);

    // layers 2,3
    dim3 gg(ceil_div(ceil_div(nE, 16), 4), R);
    k_gemm<<<gg, blk, 0, stream>>>(xb, w2b, bk_row, bk_dst, bk_coef, rbase, msgb);
    k_phaseB<<<ceil_div(nE, 4), blk, 0, stream>>>((const unsigned*)msgb, b2, col_start,
                                                  (unsigned*)xb, (unsigned*)zsb, dout, 2);
    k_gemm<<<gg, blk, 0, stream>>>(xb, w3b, bk_row, bk_dst, bk_coef, rbase, msgb);
    k_phaseB<<<ceil_div(nE, 4), blk, 0, stream>>>((const unsigned*)msgb, b3, col_start,
                                                  (unsigned*)xb, (unsigned*)zsb, dout, 3);
}

// Round 5
// 356.990 us; speedup vs baseline: 3.7364x; 1.0819x over previous
//
#include <hip/hip_runtime.h>
#include <math.h>

// Problem constants (match reference)
constexpr int EN = 200000;   // edges == nodes
constexpr int D  = 128;      // embedding dim
constexpr int R  = 4;        // relation types
constexpr float NEG = 0.01f;

static inline int ceil_div(int a, int b) { return (a + b - 1) / b; }

typedef __attribute__((ext_vector_type(8))) __bf16 bf16x8;
typedef __attribute__((ext_vector_type(4))) float f32x4;

// ---------- bf16 helpers (RNE) ----------
__device__ __forceinline__ unsigned short f2bf(float f) {
    union { float f; unsigned u; } v; v.f = f;
    unsigned u = v.u + 0x7fffu + ((v.u >> 16) & 1u);
    return (unsigned short)(u >> 16);
}
__device__ __forceinline__ unsigned pack2bf(float a, float b) {
    return (unsigned)f2bf(a) | ((unsigned)f2bf(b) << 16);
}
__device__ __forceinline__ float bflo(unsigned m) { return __uint_as_float(m << 16); }
__device__ __forceinline__ float bfhi(unsigned m) { return __uint_as_float(m & 0xffff0000u); }

// ---------- histogram: col degree (int) + relation counts ----------
__global__ void k_cnt(const int* __restrict__ col, const int* __restrict__ etype,
                      int* __restrict__ cnt, int* __restrict__ rcnt, int n) {
    __shared__ int lr[R];
    int t = threadIdx.x;
    if (t < R) lr[t] = 0;
    __syncthreads();
    int e = blockIdx.x * 256 + t;
    if (e < n) {
        atomicAdd(&cnt[col[e]], 1);
        atomicAdd(&lr[etype[e]], 1);
    }
    __syncthreads();
    if (t < R) atomicAdd(&rcnt[t], lr[t]);
}

// ---------- scan stage 1: per-1024-chunk sums ----------
__global__ void k_scan1(const int* __restrict__ cnt, int* __restrict__ part, int n) {
    __shared__ int sm[256];
    int t = threadIdx.x;
    int base = blockIdx.x * 1024 + t * 4;
    int s = 0;
    #pragma unroll
    for (int i = 0; i < 4; ++i) { int idx = base + i; if (idx < n) s += cnt[idx]; }
    sm[t] = s; __syncthreads();
    for (int off = 128; off > 0; off >>= 1) {
        if (t < off) sm[t] += sm[t + off];
        __syncthreads();
    }
    if (t == 0) part[blockIdx.x] = sm[0];
}

// ---------- scan stage 2 (+ relation-base scan + bk_row pad zero) ----------
__global__ void k_scan2(int* __restrict__ part, int nb,
                        const int* __restrict__ rcnt, int* __restrict__ rbase,
                        int* __restrict__ cursor, int* __restrict__ col_start,
                        int* __restrict__ bk_row) {
    __shared__ int sm[256];
    int t = threadIdx.x;
    sm[t] = (t < nb) ? part[t] : 0;
    __syncthreads();
    for (int off = 1; off < 256; off <<= 1) {
        int u = 0;
        if (t >= off) u = sm[t - off];
        __syncthreads();
        sm[t] += u;
        __syncthreads();
    }
    int ex = (t > 0) ? sm[t - 1] : 0;
    if (t < nb) part[t] = ex;
    if (t == 0) {
        int s = 0;
        for (int r = 0; r < R; ++r) { rbase[r] = s; cursor[r] = s; s += rcnt[r]; }
        rbase[R] = s;
        col_start[EN] = EN;
    }
    if (t >= 64 && t < 128) bk_row[EN + t - 64] = 0;   // pad: safe gather rows
}

// ---------- scan stage 3: col_start (+ ccur zeroing) ----------
__global__ void k_scan3(const int* __restrict__ cnt, const int* __restrict__ part,
                        int* __restrict__ col_start, int* __restrict__ ccur, int n) {
    __shared__ int sm[256];
    int t = threadIdx.x;
    int base = blockIdx.x * 1024 + t * 4;
    int v[4]; int s = 0;
    #pragma unroll
    for (int i = 0; i < 4; ++i) { int idx = base + i; v[i] = (idx < n) ? cnt[idx] : 0; s += v[i]; }
    sm[t] = s; __syncthreads();
    for (int off = 1; off < 256; off <<= 1) {
        int u = 0;
        if (t >= off) u = sm[t - off];
        __syncthreads();
        sm[t] += u;
        __syncthreads();
    }
    int ex = ((t > 0) ? sm[t - 1] : 0) + part[blockIdx.x];
    #pragma unroll
    for (int i = 0; i < 4; ++i) {
        int idx = base + i;
        if (idx < n) { col_start[idx] = ex; ex += v[i]; ccur[idx] = 0; }
    }
}

// ---------- bucket by relation + col-sorted placement + coef ----------
__global__ void k_bucket(const int* __restrict__ row, const int* __restrict__ col,
                         const int* __restrict__ etype, const float* __restrict__ attr,
                         const int* __restrict__ cnt, const int* __restrict__ col_start,
                         int* __restrict__ cursor, int* __restrict__ ccur,
                         int* __restrict__ bk_row, int* __restrict__ bk_dst,
                         float* __restrict__ bk_coef,
                         float* __restrict__ scoef, unsigned char* __restrict__ styp,
                         int n) {
    __shared__ int lcnt[R];
    __shared__ int lbase[R];
    int t = threadIdx.x;
    if (t < R) lcnt[t] = 0;
    __syncthreads();
    int e = blockIdx.x * 256 + t;
    int r = 0, rank = 0, c = 0, rw = 0;
    float cf = 0.f;
    if (e < n) {
        r = etype[e];
        rank = atomicAdd(&lcnt[r], 1);
        c = col[e]; rw = row[e];
        int dr = cnt[rw], dc = cnt[c];
        float a = (dr > 0) ? rsqrtf((float)dr) : 0.f;
        float b = (dc > 0) ? rsqrtf((float)dc) : 0.f;
        cf = attr[e] * a * b;
    }
    __syncthreads();
    if (t < R) lbase[t] = atomicAdd(&cursor[t], lcnt[t]);
    __syncthreads();
    if (e < n) {
        int pos = lbase[r] + rank;                       // relation-bucket position
        int sp = col_start[c] + atomicAdd(&ccur[c], 1);  // col-sorted position
        bk_row[pos] = rw;
        bk_dst[pos] = sp;
        bk_coef[pos] = cf;
        scoef[sp] = cf;
        styp[sp] = (unsigned char)r;
    }
}

// ---------- W pre-swizzle to MFMA A-frag bf16 ----------
__device__ __forceinline__ void wswz_one(const float* __restrict__ w,
                                         unsigned short* __restrict__ wsw, int t) {
    int lane = t & 63, mt = (t >> 6) & 7, s = (t >> 9) & 3, r = t >> 11;
    int q = lane >> 4, n = mt * 16 + (lane & 15);
    union { unsigned short us[8]; uint4 u4; } o;
    #pragma unroll
    for (int j = 0; j < 8; ++j) {
        int k = s * 32 + q * 8 + j;
        o.us[j] = f2bf(w[((size_t)r * D + k) * D + n]);
    }
    *(uint4*)(wsw + (size_t)t * 8) = o.u4;
}

// one kernel: swizzle W2, W3 + colsum(W1)
__global__ void k_prep(const float* __restrict__ w1, const float* __restrict__ w2,
                       const float* __restrict__ w3,
                       unsigned short* __restrict__ w2b, unsigned short* __restrict__ w3b,
                       float* __restrict__ s1) {
    int t = blockIdx.x * 256 + threadIdx.x;
    if (t < 8192) {
        wswz_one(w2, w2b, t);
    } else if (t < 16384) {
        wswz_one(w3, w3b, t - 8192);
    } else if (t < 16896) {
        int t2 = t - 16384;           // 0..511
        int r = t2 >> 7, j = t2 & (D - 1);
        float s = 0.f;
        for (int k = 0; k < D; ++k) s += w1[((r << 7) + k) * D + j];
        s1[t2] = s;
    }
}

// ---------- layer 1 gather: xb = bf16(z1) ----------
__global__ void k_phase1(const float* __restrict__ s1, const float* __restrict__ b1,
                         const int* __restrict__ col_start,
                         const unsigned char* __restrict__ styp,
                         const float* __restrict__ scoef,
                         unsigned* __restrict__ xb32) {
    __shared__ float ls1[R * D];
    __shared__ float lb[D];
    int t = threadIdx.x;
    ls1[t] = s1[t];
    ls1[t + 256] = s1[t + 256];
    if (t < D) lb[t] = b1[t];
    __syncthreads();
    int lane = t & 63;
    int c = blockIdx.x * 4 + (t >> 6);
    if (c >= EN) return;
    int st = col_start[c], en = col_start[c + 1];
    float a0 = 0.f, a1 = 0.f;
    for (int p = st; p < en; ++p) {
        float cf = scoef[p];
        int tp = styp[p];
        a0 += cf * ls1[tp * D + lane * 2];
        a1 += cf * ls1[tp * D + lane * 2 + 1];
    }
    a0 += lb[lane * 2]; a1 += lb[lane * 2 + 1];
    a0 = (a0 > 0.f) ? a0 : NEG * a0;
    a1 = (a1 > 0.f) ? a1 : NEG * a1;
    xb32[(size_t)c * 64 + lane] = pack2bf(a0, a1);
}

// ---------- MFMA GEMM: one wave per 16-edge tile ----------
// D^T = W^T (A-operand, pre-swizzled) x x^T (B-operand, row gather).
// Epilogue: per-wave LDS transpose -> 256 B contiguous row stores.
__global__ __launch_bounds__(256)
void k_gemm(const unsigned short* __restrict__ xb, const unsigned short* __restrict__ wsw,
            const int* __restrict__ bk_row, const int* __restrict__ bk_dst,
            const float* __restrict__ bk_coef, const int* __restrict__ rbase,
            unsigned short* __restrict__ msgb) {
    const int r = blockIdx.y;
    const int base = rbase[r];
    const int cnt = rbase[r + 1] - base;
    const int t = threadIdx.x;
    const int tile = blockIdx.x * 4 + (t >> 6);
    __shared__ unsigned short xpose[4][16 * 144];   // 18 KB; wave-private regions
    if (tile * 16 >= cnt) return;           // wave-uniform early exit
    const int l = t & 63, q = l >> 4, n16 = l & 15;
    const int eidx = tile * 16 + n16;
    const bool valid = eidx < cnt;
    const int p = base + eidx;              // < EN + 16 (arrays padded by 64)
    const int srow = bk_row[p];
    const int dp = bk_dst[p];
    const float cf = bk_coef[p];

    // B-frags: x[edge][k], 16 B per lane per K-step
    const unsigned short* xrow = xb + (size_t)srow * D;
    bf16x8 xf[4];
    #pragma unroll
    for (int s = 0; s < 4; ++s)
        xf[s] = *(const bf16x8*)(xrow + s * 32 + q * 8);

    // A-frags: swizzled W, L1/L2-resident
    const unsigned short* wr = wsw + ((size_t)r * 2048 + l) * 8;

    f32x4 acc[8];
    #pragma unroll
    for (int mt = 0; mt < 8; ++mt) acc[mt] = (f32x4){0.f, 0.f, 0.f, 0.f};

    #pragma unroll
    for (int s = 0; s < 4; ++s) {
        #pragma unroll
        for (int mt = 0; mt < 8; ++mt) {
            bf16x8 wf = *(const bf16x8*)(wr + (size_t)(s * 512 + mt * 64) * 8);
            acc[mt] = __builtin_amdgcn_mfma_f32_16x16x32_bf16(wf, xf[s], acc[mt], 0, 0, 0);
        }
    }

    // epilogue: scale, pack, transpose through wave-private LDS, coalesced store
    unsigned short* lbuf = xpose[t >> 6];
    const float c = valid ? cf : 0.f;
    #pragma unroll
    for (int mt = 0; mt < 8; ++mt) {
        uint2 u;
        u.x = pack2bf(acc[mt].x * c, acc[mt].y * c);
        u.y = pack2bf(acc[mt].z * c, acc[mt].w * c);
        *(uint2*)&lbuf[n16 * 144 + mt * 16 + q * 4] = u;
    }
    const int dpv = valid ? dp : EN;        // invalid edges -> dump row
    #pragma unroll
    for (int ro = 0; ro < 4; ++ro) {
        int e = ro * 4 + q;
        uint4 v = *(const uint4*)&lbuf[e * 144 + n16 * 8];
        int rdp = __shfl(dpv, e);
        *(uint4*)(msgb + (size_t)rdp * D + n16 * 8) = v;
    }
}

// ---------- sequential gather + bias + leaky + combine (layers 2,3) ----------
// mode 2: z1 = xb; xb = z2 (bf16); zsum = z1+z2 (bf16)
// mode 3: dout = (1 + zsum + z3) * 0.25 (fp32)
__global__ void k_phaseB(const unsigned* __restrict__ msgb32, const float* __restrict__ bias,
                         const int* __restrict__ col_start,
                         unsigned* __restrict__ xb32, unsigned* __restrict__ zs32,
                         float* __restrict__ dout, int mode) {
    __shared__ float lb[D];
    int t = threadIdx.x;
    if (t < D) lb[t] = bias[t];
    __syncthreads();
    int lane = t & 63;
    int c = blockIdx.x * 4 + (t >> 6);
    if (c >= EN) return;
    int st = col_start[c], en = col_start[c + 1];
    float a0 = 0.f, a1 = 0.f;
    for (int p = st; p < en; ++p) {
        unsigned m = msgb32[(size_t)p * 64 + lane];
        a0 += bflo(m); a1 += bfhi(m);
    }
    a0 += lb[lane * 2]; a1 += lb[lane * 2 + 1];
    a0 = (a0 > 0.f) ? a0 : NEG * a0;
    a1 = (a1 > 0.f) ? a1 : NEG * a1;
    size_t ix = (size_t)c * 64 + lane;
    if (mode == 2) {
        unsigned z1 = xb32[ix];
        xb32[ix] = pack2bf(a0, a1);
        zs32[ix] = pack2bf(bflo(z1) + a0, bfhi(z1) + a1);
    } else {
        unsigned zs = zs32[ix];
        float2 o;
        o.x = (1.f + bflo(zs) + a0) * 0.25f;
        o.y = (1.f + bfhi(zs) + a1) * 0.25f;
        ((float2*)(dout + (size_t)c * D))[lane] = o;
    }
}

extern "C" void kernel_launch(void* const* d_in, const int* in_sizes, int n_in,
                              void* d_out, int out_size, void* d_ws, size_t ws_size,
                              hipStream_t stream) {
    const int*   eidx = (const int*)d_in[0];     // [2, E]
    const int*   row  = eidx;
    const int*   col  = eidx + EN;
    const int*   etyp = (const int*)d_in[1];
    const float* attr = (const float*)d_in[2];
    const float* w1   = (const float*)d_in[3];
    const float* b1   = (const float*)d_in[4];
    const float* w2   = (const float*)d_in[5];
    const float* b2   = (const float*)d_in[6];
    const float* w3   = (const float*)d_in[7];
    const float* b3   = (const float*)d_in[8];
    float* dout = (float*)d_out;

    // workspace layout (~160 MB; ws is ~409.6 MB per harness poison size)
    char* wsb = (char*)d_ws;
    size_t off = 0;
    unsigned short* msgb = (unsigned short*)(wsb + off); off += (size_t)(EN + 1) * D * 2 + 512;
    unsigned short* xb   = (unsigned short*)(wsb + off); off += (size_t)EN * D * 2;
    unsigned short* zsb  = (unsigned short*)(wsb + off); off += (size_t)EN * D * 2;
    int*   col_start = (int*)(wsb + off); off += 800032;
    int*   cnt       = (int*)(wsb + off); off += (size_t)EN * 4;
    int*   rcnt      = (int*)(wsb + off); off += 16;      // contiguous after cnt!
    float* scoef     = (float*)(wsb + off); off += (size_t)EN * 4;
    unsigned char* styp = (unsigned char*)(wsb + off); off += 200064;
    int*   bk_row    = (int*)(wsb + off); off += (size_t)(EN + 64) * 4;
    int*   bk_dst    = (int*)(wsb + off); off += (size_t)(EN + 64) * 4;
    float* bk_coef   = (float*)(wsb + off); off += (size_t)(EN + 64) * 4;
    unsigned short* w2b = (unsigned short*)(wsb + off); off += 131072;
    unsigned short* w3b = (unsigned short*)(wsb + off); off += 131072;
    int*   part      = (int*)(wsb + off); off += 1024;
    int*   rbase     = (int*)(wsb + off); off += 32;
    int*   cursor    = (int*)(wsb + off); off += 16;
    float* s1        = (float*)(wsb + off); off += (size_t)R * D * 4;
    int*   ccur      = (int*)msgb;   // aliased: msgb not live until GEMM layer 2

    const int nE = EN;
    const int nBlkE = ceil_div(nE, 256);       // 782
    const int nScan = ceil_div(nE, 1024);      // 196
    dim3 blk(256);

    // histogram (one memset covers cnt + rcnt, contiguous)
    hipMemsetAsync(cnt, 0, (size_t)(nE + 4) * 4, stream);
    k_cnt<<<nBlkE, blk, 0, stream>>>(col, etyp, cnt, rcnt, nE);

    // scan cnt -> col_start; scan2 also does relation bases + bk_row pad,
    // scan3 also zeroes ccur
    k_scan1<<<nScan, blk, 0, stream>>>(cnt, part, nE);
    k_scan2<<<1, blk, 0, stream>>>(part, nScan, rcnt, rbase, cursor, col_start, bk_row);
    k_scan3<<<nScan, blk, 0, stream>>>(cnt, part, col_start, ccur, nE);

    // bucket + col-sort placement (+ coef)
    k_bucket<<<nBlkE, blk, 0, stream>>>(row, col, etyp, attr, cnt, col_start,
                                        cursor, ccur, bk_row, bk_dst, bk_coef,
                                        scoef, styp, nE);

    // weight prep: swizzle W2,W3 + colsum(W1) in one kernel
    k_prep<<<66, blk, 0, stream>>>(w1, w2, w3, w2b, w3b, s1);

    // layer 1 (x = ones)
    k_phase1<<<ceil_div(nE, 4), blk, 0, stream>>>(s1, b1, col_start, styp, scoef,
                                                  (unsigned*)xb);

    // layers 2,3
    dim3 gg(ceil_div(ceil_div(nE, 16), 4), R);
    k_gemm<<<gg, blk, 0, stream>>>(xb, w2b, bk_row, bk_dst, bk_coef, rbase, msgb);
    k_phaseB<<<ceil_div(nE, 4), blk, 0, stream>>>((const unsigned*)msgb, b2, col_start,
                                                  (unsigned*)xb, (unsigned*)zsb, dout, 2);
    k_gemm<<<gg, blk, 0, stream>>>(xb, w3b, bk_row, bk_dst, bk_coef, rbase, msgb);
    k_phaseB<<<ceil_div(nE, 4), blk, 0, stream>>>((const unsigned*)msgb, b3, col_start,
                                                  (unsigned*)xb, (unsigned*)zsb, dout, 3);
}